// Round 2
// baseline (1012.067 us; speedup 1.0000x reference)
//
#include <hip/hip_runtime.h>
#include <hip/hip_bf16.h>

#define BZn 32
#define CAPn 134
#define SEQn 144
#define INVn 16
#define ESP 1072
#define EFT 64

// ws layout (int32 words):
// [0..134]      g_rp   (CAP+1)
// [135..1206]   g_col  (ESP)
// [1207..1340]  g_inv  (CAP floats)
// [1341..1357]  f_rp   (INV+1)
// [1358..1421]  f_col  (EFT)
// [1422..1437]  f_inv  (INV floats)

__global__ __launch_bounds__(256) void build_csr_kernel(
    const int* __restrict__ ge, const int* __restrict__ fe, int* __restrict__ ws)
{
    int* g_rp  = ws;
    int* g_col = ws + 135;
    float* g_inv = (float*)(ws + 1207);
    int* f_rp  = ws + 1341;
    int* f_col = ws + 1358;
    float* f_inv = (float*)(ws + 1422);

    __shared__ int cnt[CAPn];
    __shared__ int off[CAPn];
    int t = threadIdx.x;

    for (int c = t; c < CAPn; c += 256) cnt[c] = 0;
    __syncthreads();
    for (int e = t; e < ESP; e += 256) atomicAdd(&cnt[ge[ESP + e]], 1);
    __syncthreads();
    if (t == 0) {
        int run = 0;
        for (int c = 0; c < CAPn; c++) {
            off[c] = run; g_rp[c] = run;
            g_inv[c] = 1.0f / fmaxf((float)cnt[c], 1.0f);
            run += cnt[c];
        }
        g_rp[CAPn] = run;
    }
    __syncthreads();
    for (int c = t; c < CAPn; c += 256) cnt[c] = 0;
    __syncthreads();
    for (int e = t; e < ESP; e += 256) {
        int d = ge[ESP + e];
        int p = off[d] + atomicAdd(&cnt[d], 1);
        g_col[p] = ge[e];
    }
    // feature graph (16 nodes, 64 edges)
    __syncthreads();
    if (t < INVn) cnt[t] = 0;
    __syncthreads();
    for (int e = t; e < EFT; e += 256) atomicAdd(&cnt[fe[EFT + e]], 1);
    __syncthreads();
    if (t == 0) {
        int run = 0;
        for (int c = 0; c < INVn; c++) {
            off[c] = run; f_rp[c] = run;
            f_inv[c] = 1.0f / fmaxf((float)cnt[c], 1.0f);
            run += cnt[c];
        }
        f_rp[INVn] = run;
    }
    __syncthreads();
    if (t < INVn) cnt[t] = 0;
    __syncthreads();
    for (int e = t; e < EFT; e += 256) {
        int d = fe[EFT + e];
        int p = off[d] + atomicAdd(&cnt[d], 1);
        f_col[p] = fe[e];
    }
}

__global__ __launch_bounds__(256) void fused_kernel(
    const float* __restrict__ src,
    const float* __restrict__ Wl,  const float* __restrict__ bl,
    const float* __restrict__ Wr,
    const float* __restrict__ fWl, const float* __restrict__ fbl,
    const float* __restrict__ fWr,
    const float* __restrict__ w1,  const float* __restrict__ w2,
    const float* __restrict__ fcw, const float* __restrict__ fcb,
    const int* __restrict__ ws,
    float* __restrict__ out)
{
    const int* g_rp  = ws;
    const int* g_col = ws + 135;
    const float* g_inv = (const float*)(ws + 1207);
    const int* f_rp  = ws + 1341;
    const int* f_col = ws + 1358;
    const float* f_inv = (const float*)(ws + 1422);

    // LDS (~60.5 KB total -> 2 blocks/CU)
    __shared__ float xs[SEQn + 4][INVn + 1];   // padded conv halo (rows 0,1,146,147 = 0)
    __shared__ float meanft[INVn][SEQn];       // feature-SAGE mean, [i][s]
    __shared__ float stage[SEQn][INVn + 1];    // reused: msp -> sp -> ff -> tp
    __shared__ float wlt[16][SEQn];            // fWl K-tile (16 rows of s')
    __shared__ float wrt[16][SEQn];            // fWr K-tile
    __shared__ float sWl[256], sWr[256], sbl[16];
    __shared__ float sfcw[768], sfcb[16];
    __shared__ float sw1[768], sw2[1280];      // conv weights transposed: [(i*K+k)*16+o]
    __shared__ float sfbl[SEQn];
    __shared__ int   sfrp[17], sfcol[64];
    __shared__ float sfinv[16];

    int t  = threadIdx.x;
    // XCD-aware swizzle: consecutive blockIdx round-robin over 8 XCDs; cluster
    // 4 batches' worth of blocks per XCD so gathered src slices stay L2-resident.
    int xcd  = blockIdx.x & 7;
    int slot = blockIdx.x >> 3;        // 0..535 = 4*134
    int c  = slot >> 2;                // 0..133
    int b  = xcd * 4 + (slot & 3);     // 0..31
    int bc = b * CAPn + c;
    const float* srcb = src + (size_t)b * (CAPn * SEQn * INVn);

    // ---- Phase 0a: spatial-graph gather (global, L2-resident) into regs ----
    int rs = g_rp[c], re = g_rp[c + 1];
    float idg = g_inv[c];
    float msp[9];
    #pragma unroll
    for (int r = 0; r < 9; r++) msp[r] = 0.0f;
    for (int e = rs; e < re; e++) {
        int n = g_col[e];                       // uniform -> scalar load
        const float* p = srcb + (size_t)n * (SEQn * INVn);
        #pragma unroll
        for (int r = 0; r < 9; r++)             // addr = n*2304 + idx : coalesced
            msp[r] += p[t + r * 256];
    }
    #pragma unroll
    for (int r = 0; r < 9; r++) msp[r] *= idg;

    // ---- Phase 0b: cooperative LDS staging ----
    for (int u = t; u < (SEQn + 4) * INVn; u += 256) {
        int s = u >> 4, i = u & 15;
        int ss = s - 2;
        float v = 0.0f;
        if (ss >= 0 && ss < SEQn)
            v = srcb[((size_t)c * SEQn + ss) * INVn + i];
        xs[s][i] = v;
    }
    sWl[t] = Wl[t];
    sWr[t] = Wr[t];
    if (t < 16) { sbl[t] = bl[t]; sfcb[t] = fcb[t]; sfinv[t] = f_inv[t]; }
    if (t < 17) sfrp[t] = f_rp[t];
    if (t < 64) sfcol[t] = f_col[t];
    for (int u = t; u < 768; u += 256) sfcw[u] = fcw[u];
    for (int u = t; u < 768; u += 256) {        // conv1 (o,i,k) -> [(i*3+k)*16+o]
        int o = u / 48, rm = u - o * 48, i = rm / 3, k = rm - i * 3;
        sw1[(i * 3 + k) * 16 + o] = w1[u];
    }
    for (int u = t; u < 1280; u += 256) {       // conv2 (o,i,k) -> [(i*5+k)*16+o]
        int o = u / 80, rm = u - o * 80, i = rm / 5, k = rm - i * 5;
        sw2[(i * 5 + k) * 16 + o] = w2[u];
    }
    for (int u = t; u < SEQn; u += 256) sfbl[u] = fbl[u];
    #pragma unroll
    for (int r = 0; r < 9; r++) {               // msp -> stage
        int idx = t + r * 256;
        stage[idx >> 4][idx & 15] = msp[r];
    }
    __syncthreads();

    // ---- Phase 1: spatial SAGE (regs) + feature-SAGE mean (LDS) ----
    float spv[9];
    #pragma unroll
    for (int r = 0; r < 9; r++) {
        int idx = t + r * 256; int s = idx >> 4, i = idx & 15;
        float a = sbl[i];
        #pragma unroll
        for (int j = 0; j < 16; j++)
            a += stage[s][j] * sWl[j * 16 + i] + xs[s + 2][j] * sWr[j * 16 + i];
        spv[r] = a;
    }
    #pragma unroll
    for (int r = 0; r < 9; r++) {
        int idx = t + r * 256; int fi = idx / SEQn, fs = idx - fi * SEQn;
        float a = 0.0f;
        int es = sfrp[fi], ee = sfrp[fi + 1];
        for (int e = es; e < ee; e++) a += xs[fs + 2][sfcol[e]];
        meanft[fi][fs] = a * sfinv[fi];
    }
    __syncthreads();   // all Phase-1 stage reads complete before rewrite

    // ---- Phase 2: sp -> stage; preload ff weight tile 0 ----
    #pragma unroll
    for (int r = 0; r < 9; r++) { int idx = t + r * 256; stage[idx >> 4][idx & 15] = spv[r]; }
    for (int u = t; u < 16 * SEQn; u += 256) {
        int q = u / SEQn, s = u - q * SEQn;
        wlt[q][s] = fWl[q * SEQn + s];
        wrt[q][s] = fWr[q * SEQn + s];
    }
    __syncthreads();

    // ---- Phase 3: consume sp into register accumulator (init src + fc_b) ----
    float accr[9];
    #pragma unroll
    for (int r = 0; r < 9; r++) {
        int idx = t + r * 256; int s = idx >> 4, i = idx & 15;
        float a = xs[s + 2][i] + sfcb[i];
        #pragma unroll
        for (int j = 0; j < 16; j++) a += stage[s][j] * sfcw[j * 16 + i];
        accr[r] = a;
    }

    // ---- Phase 4: feature SAGE matmuls (16x144)@(144x144) x2, K-tiled ----
    int fi = t >> 4;                 // 0..15 : feature-node (output row)
    int s0 = (t & 15) * 9;           // 9 contiguous output columns per thread
    float ffa[9];
    #pragma unroll
    for (int r = 0; r < 9; r++) ffa[r] = 0.0f;
    for (int tl = 0; tl < 9; tl++) {
        #pragma unroll
        for (int q = 0; q < 16; q++) {
            int sp_ = tl * 16 + q;
            float m  = meanft[fi][sp_];      // broadcast within i-group
            float xv = xs[sp_ + 2][fi];      // x2[i][s'] broadcast
            #pragma unroll
            for (int r = 0; r < 9; r++)
                ffa[r] += m * wlt[q][s0 + r] + xv * wrt[q][s0 + r];
        }
        __syncthreads();
        if (tl < 8) {
            int base = (tl + 1) * 16;
            for (int u = t; u < 16 * SEQn; u += 256) {
                int q = u / SEQn, s = u - q * SEQn;
                wlt[q][s] = fWl[(base + q) * SEQn + s];
                wrt[q][s] = fWr[(base + q) * SEQn + s];
            }
        }
        __syncthreads();
    }
    #pragma unroll
    for (int r = 0; r < 9; r++) stage[s0 + r][fi] = ffa[r] + sfbl[s0 + r];
    __syncthreads();

    // ---- Phase 5: consume ff ----
    #pragma unroll
    for (int r = 0; r < 9; r++) {
        int idx = t + r * 256; int s = idx >> 4, i = idx & 15;
        float a = 0.0f;
        #pragma unroll
        for (int j = 0; j < 16; j++) a += stage[s][j] * sfcw[(16 + j) * 16 + i];
        accr[r] += a;
    }

    // ---- Phase 6: temporal conv (k=3 pad1 + k=5 pad2) ----
    int o  = t & 15;
    int sg = t >> 4;                 // 9 contiguous s per thread
    float tpa[9];
    #pragma unroll
    for (int r = 0; r < 9; r++) tpa[r] = 0.0f;
    #pragma unroll
    for (int i = 0; i < 16; i++) {
        float xv[13];
        #pragma unroll
        for (int u = 0; u < 13; u++) xv[u] = xs[sg * 9 + u][i];
        float w1v[3], w2v[5];
        #pragma unroll
        for (int k = 0; k < 3; k++) w1v[k] = sw1[(i * 3 + k) * 16 + o];
        #pragma unroll
        for (int k = 0; k < 5; k++) w2v[k] = sw2[(i * 5 + k) * 16 + o];
        #pragma unroll
        for (int r = 0; r < 9; r++) {
            float a = xv[r + 1] * w1v[0] + xv[r + 2] * w1v[1] + xv[r + 3] * w1v[2];
            a += xv[r] * w2v[0] + xv[r + 1] * w2v[1] + xv[r + 2] * w2v[2]
               + xv[r + 3] * w2v[3] + xv[r + 4] * w2v[4];
            tpa[r] += a;
        }
    }
    __syncthreads();
    #pragma unroll
    for (int r = 0; r < 9; r++) stage[sg * 9 + r][o] = tpa[r];
    __syncthreads();

    // ---- Phase 7: consume tp, write out (coalesced fp32) ----
    float* outb = out + (size_t)bc * (SEQn * INVn);
    #pragma unroll
    for (int r = 0; r < 9; r++) {
        int idx = t + r * 256; int s = idx >> 4, i = idx & 15;
        float a = accr[r];
        #pragma unroll
        for (int j = 0; j < 16; j++) a += stage[s][j] * sfcw[(32 + j) * 16 + i];
        outb[idx] = a;
    }
}

extern "C" void kernel_launch(void* const* d_in, const int* in_sizes, int n_in,
                              void* d_out, int out_size, void* d_ws, size_t ws_size,
                              hipStream_t stream)
{
    const float* src = (const float*)d_in[0];
    const int* ge = (const int*)d_in[1];
    const int* fe = (const int*)d_in[2];
    const float* Wl  = (const float*)d_in[3];
    const float* blp = (const float*)d_in[4];
    const float* Wr  = (const float*)d_in[5];
    const float* fWl = (const float*)d_in[6];
    const float* fbl = (const float*)d_in[7];
    const float* fWr = (const float*)d_in[8];
    const float* w1  = (const float*)d_in[9];
    const float* w2  = (const float*)d_in[10];
    const float* fcw = (const float*)d_in[11];
    const float* fcb = (const float*)d_in[12];
    float* out = (float*)d_out;
    int* ws = (int*)d_ws;

    hipLaunchKernelGGL(build_csr_kernel, dim3(1), dim3(256), 0, stream, ge, fe, ws);
    hipLaunchKernelGGL(fused_kernel, dim3(BZn * CAPn), dim3(256), 0, stream,
                       src, Wl, blp, Wr, fWl, fbl, fWr, w1, w2, fcw, fcb, ws, out);
}

// Round 3
// 203.107 us; speedup vs baseline: 4.9829x; 4.9829x over previous
//
#include <hip/hip_runtime.h>

#define BZn 32
#define CAPn 134
#define SEQn 144
#define INVn 16
#define ESP 1072
#define EFT 64

// ws layout:
// words [0..134]      g_rp   (CAP+1)
// words [135..1206]   g_col  (ESP)
// words [1207..1340]  g_inv  (CAP floats)
// words [1341..1357]  f_rp   (INV+1)
// words [1358..1421]  f_col  (EFT)
// words [1422..1437]  f_inv  (INV floats)
// byte 8192:  featB  41472 bf16 (82944 B)  — feature GEMM B fragments
// byte 91136: convA   2048 bf16 (4096 B)   — conv A fragments
// byte 95232: spB      512 bf16 (1024 B)   — spatial B fragments
// byte 96256: fcB     1024 bf16 (2048 B)   — FC B fragments
// total 98304 B

typedef __attribute__((ext_vector_type(8))) short bf16x8;
typedef __attribute__((ext_vector_type(4))) short short4v;
typedef __attribute__((ext_vector_type(4))) float f32x4;

#define MFMA(a, b, c) __builtin_amdgcn_mfma_f32_16x16x32_bf16(a, b, c, 0, 0, 0)

__device__ __forceinline__ unsigned short f2bf(float f) {
    union { float f; unsigned u; } v; v.f = f;
    unsigned r = v.u + 0x7fff + ((v.u >> 16) & 1);
    return (unsigned short)(r >> 16);
}
__device__ __forceinline__ float bf2f(unsigned short h) {
    union { unsigned u; float f; } v; v.u = ((unsigned)h) << 16;
    return v.f;
}

// grid=8 blocks: block 0 builds CSR; all blocks pack weights to bf16 fragments.
__global__ __launch_bounds__(256) void prep_kernel(
    const int* __restrict__ ge, const int* __restrict__ fe,
    const float* __restrict__ Wl,  const float* __restrict__ Wr,
    const float* __restrict__ fWl, const float* __restrict__ fWr,
    const float* __restrict__ w1,  const float* __restrict__ w2,
    const float* __restrict__ fcw,
    int* __restrict__ ws)
{
    int t = threadIdx.x;
    char* wsb = (char*)ws;
    unsigned short* featB = (unsigned short*)(wsb + 8192);
    unsigned short* convA = (unsigned short*)(wsb + 91136);
    unsigned short* spB   = (unsigned short*)(wsb + 95232);
    unsigned short* fcB   = (unsigned short*)(wsb + 96256);

    if (blockIdx.x == 0) {
        int* g_rp  = ws;
        int* g_col = ws + 135;
        float* g_inv = (float*)(ws + 1207);
        int* f_rp  = ws + 1341;
        int* f_col = ws + 1358;
        float* f_inv = (float*)(ws + 1422);
        __shared__ int cnt[CAPn];
        __shared__ int off[CAPn];
        for (int c = t; c < CAPn; c += 256) cnt[c] = 0;
        __syncthreads();
        for (int e = t; e < ESP; e += 256) atomicAdd(&cnt[ge[ESP + e]], 1);
        __syncthreads();
        if (t == 0) {
            int run = 0;
            for (int c = 0; c < CAPn; c++) {
                off[c] = run; g_rp[c] = run;
                g_inv[c] = 1.0f / fmaxf((float)cnt[c], 1.0f);
                run += cnt[c];
            }
            g_rp[CAPn] = run;
        }
        __syncthreads();
        for (int c = t; c < CAPn; c += 256) cnt[c] = 0;
        __syncthreads();
        for (int e = t; e < ESP; e += 256) {
            int d = ge[ESP + e];
            int p = off[d] + atomicAdd(&cnt[d], 1);
            g_col[p] = ge[e];
        }
        __syncthreads();
        if (t < INVn) cnt[t] = 0;
        __syncthreads();
        for (int e = t; e < EFT; e += 256) atomicAdd(&cnt[fe[EFT + e]], 1);
        __syncthreads();
        if (t == 0) {
            int run = 0;
            for (int c = 0; c < INVn; c++) {
                off[c] = run; f_rp[c] = run;
                f_inv[c] = 1.0f / fmaxf((float)cnt[c], 1.0f);
                run += cnt[c];
            }
            f_rp[INVn] = run;
        }
        __syncthreads();
        if (t < INVn) cnt[t] = 0;
        __syncthreads();
        for (int e = t; e < EFT; e += 256) {
            int d = fe[EFT + e];
            int p = off[d] + atomicAdd(&cnt[d], 1);
            f_col[p] = fe[e];
        }
    }

    int gt = blockIdx.x * 256 + t;
    int gs = gridDim.x * 256;
    // featB[((kk*9+n0)*64+l)*8+j] = W[k=kk*32+(l>>4)*8+j][s=n0*16+(l&15)], W=[fWl;fWr]
    for (int u = gt; u < 41472; u += gs) {
        int kk = u / 4608, rem = u - kk * 4608;
        int n0 = rem >> 9, rem2 = rem & 511;
        int l = rem2 >> 3, j = rem2 & 7;
        int k = kk * 32 + (l >> 4) * 8 + j;
        int s = n0 * 16 + (l & 15);
        float v = (k < 144) ? fWl[k * 144 + s] : fWr[(k - 144) * 144 + s];
        featB[u] = f2bf(v);
    }
    // convA[(kk*64+l)*8+j] = Wc[o=l&15][k=kk*32+q*8+j], k=tap*16+i packing
    for (int u = gt; u < 2048; u += gs) {
        int kk = u >> 9, rem = u & 511;
        int l = rem >> 3, j = rem & 7;
        int q = l >> 4, o = l & 15;
        int kkp = kk * 2 + (q >> 1);
        int i = (q & 1) * 8 + j;
        float v = (kkp < 3) ? w1[(o * 16 + i) * 3 + kkp] : w2[(o * 16 + i) * 5 + (kkp - 3)];
        convA[u] = f2bf(v);
    }
    // spB[l*8+j] = [Wl;Wr][k=(l>>4)*8+j][i=l&15]
    for (int u = gt; u < 512; u += gs) {
        int l = u >> 3, j = u & 7;
        int k = (l >> 4) * 8 + j, i = l & 15;
        float v = (k < 16) ? Wl[k * 16 + i] : Wr[(k - 16) * 16 + i];
        spB[u] = f2bf(v);
    }
    // fcB[(kk*64+l)*8+j] = fcw[k][i] zero-padded to K=64
    for (int u = gt; u < 1024; u += gs) {
        int kk = u >> 9, rem = u & 511;
        int l = rem >> 3, j = rem & 7;
        int k = kk * 32 + (l >> 4) * 8 + j, i = l & 15;
        float v = (k < 48) ? fcw[k * 16 + i] : 0.0f;
        fcB[u] = f2bf(v);
    }
}

__global__ __launch_bounds__(256, 3) void fused_kernel(
    const float* __restrict__ src,
    const float* __restrict__ bl,  const float* __restrict__ fbl,
    const float* __restrict__ fcb,
    const int* __restrict__ ws,
    float* __restrict__ out)
{
    const int* g_rp  = ws;
    const int* g_col = ws + 135;
    const float* g_inv = (const float*)(ws + 1207);
    const int* f_rp  = ws + 1341;
    const int* f_col = ws + 1358;
    const float* f_inv = (const float*)(ws + 1422);
    const char* wsb = (const char*)ws;
    const unsigned short* featB = (const unsigned short*)(wsb + 8192);
    const unsigned short* convA = (const unsigned short*)(wsb + 91136);
    const unsigned short* spB   = (const unsigned short*)(wsb + 95232);
    const unsigned short* fcB   = (const unsigned short*)(wsb + 96256);

    // bf16 LDS tiles; row strides 24 / 152 shorts keep bank aliasing <= 2-way (free)
    __shared__ __align__(16) unsigned short xs_bf[SEQn + 4][24];     // halo rows 0,1,146,147 = 0
    __shared__ __align__(16) unsigned short xT_bf[INVn][152];        // x^T  [i][s]
    __shared__ __align__(16) unsigned short meanft_bf[INVn][152];    // feature mean [i][s]
    __shared__ __align__(16) unsigned short mean_sp_bf[SEQn][24];    // spatial mean [s][i]
    __shared__ __align__(16) unsigned short sp_bf[SEQn][24];
    __shared__ __align__(16) unsigned short ff_bf[SEQn][24];
    __shared__ __align__(16) unsigned short tp_bf[SEQn][24];
    __shared__ float sbl[16], sfcb[16], sfinv[16], sfbl[SEQn];
    __shared__ int   sfrp[17], sfcol[64];

    int t = threadIdx.x;
    int wave = t >> 6, lane = t & 63;
    int q = lane >> 4, ln = lane & 15;

    // XCD-aware swizzle: keep each batch's blocks on one XCD for src L2 locality
    int xcd  = blockIdx.x & 7;
    int slot = blockIdx.x >> 3;
    int c  = slot >> 2;
    int b  = xcd * 4 + (slot & 3);
    int bc = b * CAPn + c;
    const float* srcb = src + (size_t)b * (CAPn * SEQn * INVn);
    const float* srcc = srcb + (size_t)c * (SEQn * INVn);

    // ---- Stage 1: spatial-graph gather (global) + staging (no LDS deps) ----
    int rs = g_rp[c], re = g_rp[c + 1];
    float idg = g_inv[c];
    float msp[9];
    #pragma unroll
    for (int r = 0; r < 9; r++) msp[r] = 0.0f;
    for (int e = rs; e < re; e++) {
        int n = g_col[e];
        const float* p = srcb + (size_t)n * (SEQn * INVn);
        #pragma unroll
        for (int r = 0; r < 9; r++) msp[r] += p[t + r * 256];
    }
    #pragma unroll
    for (int r = 0; r < 9; r++) {
        int idx = t + r * 256;
        mean_sp_bf[idx >> 4][idx & 15] = f2bf(msp[r] * idg);
    }
    for (int u = t; u < SEQn * INVn; u += 256) {
        int s = u >> 4, i = u & 15;
        unsigned short hv = f2bf(srcc[u]);
        xs_bf[s + 2][i] = hv;
        xT_bf[i][s] = hv;
    }
    if (t < 64) {                                 // conv halo zeros
        int r = t >> 4, i = t & 15;
        int row = (r < 2) ? r : 144 + r;          // 0,1,146,147
        xs_bf[row][i] = 0;
    }
    if (t < 16) { sbl[t] = bl[t]; sfcb[t] = fcb[t]; sfinv[t] = f_inv[t]; }
    if (t < 17) sfrp[t] = f_rp[t];
    if (t < 64) sfcol[t] = f_col[t];
    if (t < SEQn) sfbl[t] = fbl[t];
    __syncthreads();

    // ---- Stage 2: feature-graph mean (from xs_bf) ----
    for (int u = t; u < INVn * SEQn; u += 256) {
        int fi = u / SEQn, fs = u - fi * SEQn;
        float a = 0.0f;
        int es = sfrp[fi], ee = sfrp[fi + 1];
        for (int e = es; e < ee; e++) a += bf2f(xs_bf[fs + 2][sfcol[e]]);
        meanft_bf[fi][fs] = f2bf(a * sfinv[fi]);
    }
    __syncthreads();

    // ---- Stage 3: MFMA GEMMs, hand-balanced across 4 waves (30/32/32/32) ----
    const int fst[4] = {0, 3, 5, 7}, fcn[4] = {3, 2, 2, 2};   // feature N-tiles
    const int cst[4] = {0, 0, 3, 6}, ccn[4] = {0, 3, 3, 3};   // conv N-tiles
    const int sst[4] = {0, 3, 5, 7}, scn[4] = {3, 2, 2, 2};   // spatial M-tiles

    // feature: out2[i,s] = sum_k [meanft|xT][i,k] * [fWl;fWr][k,s], K=288
    for (int tt = 0; tt < fcn[wave]; tt++) {
        int n0 = fst[wave] + tt;
        int sl = n0 * 16 + ln;
        f32x4 acc = {0.f, 0.f, 0.f, 0.f};
        #pragma unroll
        for (int kk = 0; kk < 9; kk++) {
            int koff = kk * 32 + q * 8;
            const unsigned short* ap = (koff < 144) ? &meanft_bf[ln][koff]
                                                    : &xT_bf[ln][koff - 144];
            bf16x8 a = *(const bf16x8*)ap;
            bf16x8 bfr = *(const bf16x8*)(featB + ((kk * 9 + n0) * 64 + lane) * 8);
            acc = MFMA(a, bfr, acc);
        }
        float fb = sfbl[sl];
        short4v pk;
        #pragma unroll
        for (int r = 0; r < 4; r++) pk[r] = (short)f2bf(acc[r] + fb);
        *(short4v*)&ff_bf[sl][q * 4] = pk;        // ff[s][i0=q*4..+3]
    }
    // conv: out_t[o,s], K=128 im2col (k = tap*16 + i); B-frag = one b128 from xs_bf
    for (int tt = 0; tt < ccn[wave]; tt++) {
        int n0 = cst[wave] + tt;
        int sl = n0 * 16 + ln;
        f32x4 acc = {0.f, 0.f, 0.f, 0.f};
        #pragma unroll
        for (int kk = 0; kk < 4; kk++) {
            int kkp = kk * 2 + (q >> 1);
            int off = (kkp < 3) ? (kkp - 1) : (kkp - 5);
            int i0 = (q & 1) * 8;
            bf16x8 a = *(const bf16x8*)(convA + (kk * 64 + lane) * 8);
            bf16x8 bfr = *(const bf16x8*)&xs_bf[sl + 2 + off][i0];
            acc = MFMA(a, bfr, acc);
        }
        short4v pk;
        #pragma unroll
        for (int r = 0; r < 4; r++) pk[r] = (short)f2bf(acc[r]);
        *(short4v*)&tp_bf[sl][q * 4] = pk;        // tp[s][o=q*4..+3]
    }
    // spatial: out_sp[s,i] = [mean_sp|x][s,k32] @ [Wl;Wr][k,i]
    for (int tt = 0; tt < scn[wave]; tt++) {
        int mt = sst[wave] + tt;
        int sl = mt * 16 + ln;
        const unsigned short* ap = (q < 2) ? &mean_sp_bf[sl][(q & 1) * 8]
                                           : &xs_bf[sl + 2][(q & 1) * 8];
        bf16x8 a = *(const bf16x8*)ap;
        bf16x8 bfr = *(const bf16x8*)(spB + lane * 8);
        f32x4 acc = {0.f, 0.f, 0.f, 0.f};
        acc = MFMA(a, bfr, acc);
        #pragma unroll
        for (int r = 0; r < 4; r++) {
            int so = mt * 16 + q * 4 + r;
            sp_bf[so][ln] = f2bf(acc[r] + sbl[ln]);
        }
    }
    __syncthreads();

    // ---- Stage 4: FC (K=64: [sp|ff|tp|0]) + residual + store ----
    for (int tt = 0; tt < fcn[wave]; tt++) {
        int mt = fst[wave] + tt;
        int sl = mt * 16 + ln;
        f32x4 acc = {0.f, 0.f, 0.f, 0.f};
        {   // kk=0: quads read sp lo/hi, ff lo/hi
            const unsigned short* ap = (q < 2) ? &sp_bf[sl][(q & 1) * 8]
                                               : &ff_bf[sl][(q & 1) * 8];
            bf16x8 a = *(const bf16x8*)ap;
            bf16x8 bfr = *(const bf16x8*)(fcB + lane * 8);
            acc = MFMA(a, bfr, acc);
        }
        {   // kk=1: quads 0,1 read tp; quads 2,3 zero
            bf16x8 a = {0, 0, 0, 0, 0, 0, 0, 0};
            if (q < 2) a = *(const bf16x8*)&tp_bf[sl][q * 8];
            bf16x8 bfr = *(const bf16x8*)(fcB + (64 + lane) * 8);
            acc = MFMA(a, bfr, acc);
        }
        float* outb = out + (size_t)bc * (SEQn * INVn);
        #pragma unroll
        for (int r = 0; r < 4; r++) {
            int so = mt * 16 + q * 4 + r;
            int idx = so * 16 + ln;
            outb[idx] = acc[r] + sfcb[ln] + srcc[idx];   // fp32 residual
        }
    }
}

extern "C" void kernel_launch(void* const* d_in, const int* in_sizes, int n_in,
                              void* d_out, int out_size, void* d_ws, size_t ws_size,
                              hipStream_t stream)
{
    const float* src = (const float*)d_in[0];
    const int* ge = (const int*)d_in[1];
    const int* fe = (const int*)d_in[2];
    const float* Wl  = (const float*)d_in[3];
    const float* blp = (const float*)d_in[4];
    const float* Wr  = (const float*)d_in[5];
    const float* fWl = (const float*)d_in[6];
    const float* fbl = (const float*)d_in[7];
    const float* fWr = (const float*)d_in[8];
    const float* w1  = (const float*)d_in[9];
    const float* w2  = (const float*)d_in[10];
    const float* fcw = (const float*)d_in[11];
    const float* fcb = (const float*)d_in[12];
    float* out = (float*)d_out;
    int* ws = (int*)d_ws;

    hipLaunchKernelGGL(prep_kernel, dim3(8), dim3(256), 0, stream,
                       ge, fe, Wl, Wr, fWl, fWr, w1, w2, fcw, ws);
    hipLaunchKernelGGL(fused_kernel, dim3(BZn * CAPn), dim3(256), 0, stream,
                       src, blp, fbl, fcb, ws, out);
}

// Round 4
// 175.368 us; speedup vs baseline: 5.7711x; 1.1582x over previous
//
#include <hip/hip_runtime.h>
#include <hip/hip_bf16.h>

#define BZn 32
#define CAPn 134
#define SEQn 144
#define INVn 16
#define ESP 1072
#define EFT 64

// ws layout:
// words [0..134]      g_rp   (CAP+1)
// words [135..1206]   g_col  (ESP)
// words [1207..1340]  g_inv  (CAP floats)
// byte 6144:  ftB     512 bf16 (1024 B)   — feature-adjacency B fragments (K=32 pad, inv folded)
// byte 8192:  featB 41472 bf16 (82944 B)  — feature GEMM B fragments
// byte 91136: convA  2048 bf16 (4096 B)   — conv A fragments
// byte 95232: spB     512 bf16 (1024 B)   — spatial B fragments
// byte 96256: fcB    1024 bf16 (2048 B)   — FC B fragments
// total 98304 B

typedef __attribute__((ext_vector_type(8))) short bf16x8;
typedef __attribute__((ext_vector_type(4))) short short4v;
typedef __attribute__((ext_vector_type(4))) float f32x4;

#define MFMA(a, b, c) __builtin_amdgcn_mfma_f32_16x16x32_bf16(a, b, c, 0, 0, 0)

__device__ __forceinline__ unsigned short f2bf(float f) {
    union { float f; unsigned u; } v; v.f = f;
    unsigned r = v.u + 0x7fff + ((v.u >> 16) & 1);
    return (unsigned short)(r >> 16);
}
__device__ __forceinline__ unsigned pk2(float a, float b) {
    float2 v; v.x = a; v.y = b;
    union { __hip_bfloat162 h; unsigned u; } c;
    c.h = __float22bfloat162_rn(v);          // v_cvt_pk_bf16_f32 on gfx950
    return c.u;
}
__device__ __forceinline__ short4v pack4(f32x4 v) {
    union { unsigned u[2]; short4v s; } r;
    r.u[0] = pk2(v[0], v[1]);
    r.u[1] = pk2(v[2], v[3]);
    return r.s;
}

// grid=16: block 0 builds CSR + feature-adjacency; all blocks pack weights.
__global__ __launch_bounds__(256) void prep_kernel(
    const int* __restrict__ ge, const int* __restrict__ fe,
    const float* __restrict__ Wl,  const float* __restrict__ Wr,
    const float* __restrict__ fWl, const float* __restrict__ fWr,
    const float* __restrict__ w1,  const float* __restrict__ w2,
    const float* __restrict__ fcw,
    int* __restrict__ ws)
{
    int t = threadIdx.x;
    char* wsb = (char*)ws;
    unsigned short* ftB   = (unsigned short*)(wsb + 6144);
    unsigned short* featB = (unsigned short*)(wsb + 8192);
    unsigned short* convA = (unsigned short*)(wsb + 91136);
    unsigned short* spB   = (unsigned short*)(wsb + 95232);
    unsigned short* fcB   = (unsigned short*)(wsb + 96256);

    if (blockIdx.x == 0) {
        int* g_rp  = ws;
        int* g_col = ws + 135;
        float* g_inv = (float*)(ws + 1207);
        __shared__ int cnt[CAPn];
        __shared__ int off[CAPn];
        __shared__ int fm[256];
        __shared__ float finv[16];
        for (int c = t; c < CAPn; c += 256) cnt[c] = 0;
        fm[t] = 0;
        __syncthreads();
        for (int e = t; e < ESP; e += 256) atomicAdd(&cnt[ge[ESP + e]], 1);
        if (t < EFT) atomicAdd(&fm[fe[t] * 16 + fe[EFT + t]], 1);
        __syncthreads();
        if (t == 0) {
            int run = 0;
            for (int c = 0; c < CAPn; c++) {
                off[c] = run; g_rp[c] = run;
                g_inv[c] = 1.0f / fmaxf((float)cnt[c], 1.0f);
                run += cnt[c];
            }
            g_rp[CAPn] = run;
        }
        if (t < 16) {
            int dg = 0;
            for (int j = 0; j < 16; j++) dg += fm[j * 16 + t];
            finv[t] = 1.0f / fmaxf((float)dg, 1.0f);
        }
        __syncthreads();
        for (int c = t; c < CAPn; c += 256) cnt[c] = 0;
        __syncthreads();
        for (int e = t; e < ESP; e += 256) {
            int d = ge[ESP + e];
            int p = off[d] + atomicAdd(&cnt[d], 1);
            g_col[p] = ge[e];
        }
        // ftB[l*8+j] = (k<16 ? fm[k][i]*finv[i] : 0), k=(l>>4)*8+j, i=l&15
        for (int u = t; u < 512; u += 256) {
            int l = u >> 3, j = u & 7;
            int k = (l >> 4) * 8 + j, i = l & 15;
            float v = (k < 16) ? (float)fm[k * 16 + i] * finv[i] : 0.0f;
            ftB[u] = f2bf(v);
        }
    }

    int gt = blockIdx.x * 256 + t;
    int gs = gridDim.x * 256;
    // featB[((kk*9+n0)*64+l)*8+j] = W[k=kk*32+(l>>4)*8+j][s=n0*16+(l&15)], W=[fWl;fWr]
    for (int u = gt; u < 41472; u += gs) {
        int kk = u / 4608, rem = u - kk * 4608;
        int n0 = rem >> 9, rem2 = rem & 511;
        int l = rem2 >> 3, j = rem2 & 7;
        int k = kk * 32 + (l >> 4) * 8 + j;
        int s = n0 * 16 + (l & 15);
        float v = (k < 144) ? fWl[k * 144 + s] : fWr[(k - 144) * 144 + s];
        featB[u] = f2bf(v);
    }
    // convA[(kk*64+l)*8+j] = Wc[o=l&15][k], k=tap*16+i packing
    for (int u = gt; u < 2048; u += gs) {
        int kk = u >> 9, rem = u & 511;
        int l = rem >> 3, j = rem & 7;
        int q = l >> 4, o = l & 15;
        int kkp = kk * 2 + (q >> 1);
        int i = (q & 1) * 8 + j;
        float v = (kkp < 3) ? w1[(o * 16 + i) * 3 + kkp] : w2[(o * 16 + i) * 5 + (kkp - 3)];
        convA[u] = f2bf(v);
    }
    // spB[l*8+j] = [Wl;Wr][k=(l>>4)*8+j][i=l&15]
    for (int u = gt; u < 512; u += gs) {
        int l = u >> 3, j = u & 7;
        int k = (l >> 4) * 8 + j, i = l & 15;
        float v = (k < 16) ? Wl[k * 16 + i] : Wr[(k - 16) * 16 + i];
        spB[u] = f2bf(v);
    }
    // fcB[(kk*64+l)*8+j] = fcw[k][i] zero-padded to K=64
    for (int u = gt; u < 1024; u += gs) {
        int kk = u >> 9, rem = u & 511;
        int l = rem >> 3, j = rem & 7;
        int k = kk * 32 + (l >> 4) * 8 + j, i = l & 15;
        float v = (k < 48) ? fcw[k * 16 + i] : 0.0f;
        fcB[u] = f2bf(v);
    }
}

__global__ __launch_bounds__(256, 3) void fused_kernel(
    const float* __restrict__ src,
    const float* __restrict__ bl,  const float* __restrict__ fbl,
    const float* __restrict__ fcb,
    const int* __restrict__ ws,
    float* __restrict__ out)
{
    const int* g_rp  = ws;
    const int* g_col = ws + 135;
    const float* g_inv = (const float*)(ws + 1207);
    const char* wsb = (const char*)ws;
    const unsigned short* ftB   = (const unsigned short*)(wsb + 6144);
    const unsigned short* featB = (const unsigned short*)(wsb + 8192);
    const unsigned short* convA = (const unsigned short*)(wsb + 91136);
    const unsigned short* spB   = (const unsigned short*)(wsb + 95232);
    const unsigned short* fcB   = (const unsigned short*)(wsb + 96256);

    // bf16 LDS tiles; strides 24 / 152 shorts: 16B-aligned rows, <=2-way banks
    __shared__ __align__(16) unsigned short xs_bf[SEQn + 4][24];
    __shared__ __align__(16) unsigned short xT_bf[INVn][152];
    __shared__ __align__(16) unsigned short meanft_bf[INVn][152];
    __shared__ __align__(16) unsigned short mean_sp_bf[SEQn][24];
    __shared__ __align__(16) unsigned short sp_bf[SEQn][24];
    __shared__ __align__(16) unsigned short ff_bf[SEQn][24];
    __shared__ __align__(16) unsigned short tp_bf[SEQn][24];
    __shared__ float sbl[16], sfcb[16], sfbl[SEQn];

    int t = threadIdx.x;
    int wave = t >> 6, lane = t & 63;
    int q = lane >> 4, ln = lane & 15;

    int xcd  = blockIdx.x & 7;
    int slot = blockIdx.x >> 3;
    int c  = slot >> 2;
    int b  = xcd * 4 + (slot & 3);
    int bc = b * CAPn + c;
    const float* srcb = src + (size_t)b * (CAPn * SEQn * INVn);
    const float* srcc = srcb + (size_t)c * (SEQn * INVn);

    // hoisted tile-invariant MFMA fragments (global, L2-hot; no LDS dep)
    bf16x8 caf[4];
    #pragma unroll
    for (int kk = 0; kk < 4; kk++)
        caf[kk] = *(const bf16x8*)(convA + (kk * 64 + lane) * 8);
    bf16x8 sbf  = *(const bf16x8*)(spB + lane * 8);
    bf16x8 ftf  = *(const bf16x8*)(ftB + lane * 8);
    bf16x8 fcf0 = *(const bf16x8*)(fcB + lane * 8);
    bf16x8 fcf1 = *(const bf16x8*)(fcB + (64 + lane) * 8);

    // ---- Stage 1: float4 spatial gather + float4 staging ----
    int rs = g_rp[c], re = g_rp[c + 1];
    float idg = g_inv[c];
    f32x4 m0 = {0.f,0.f,0.f,0.f}, m1 = {0.f,0.f,0.f,0.f}, m2 = {0.f,0.f,0.f,0.f};
    for (int e = rs; e < re; e++) {
        int n = g_col[e];                              // block-uniform -> s_load
        const f32x4* p4 = (const f32x4*)(srcb + (size_t)n * (SEQn * INVn));
        m0 += p4[t];
        m1 += p4[t + 256];
        if (t < 64) m2 += p4[t + 512];                 // wave-0 only, uniform
    }
    int s0g = t >> 2, i0g = (t & 3) * 4;
    m0 *= idg; m1 *= idg; m2 *= idg;
    *(short4v*)&mean_sp_bf[s0g][i0g]       = pack4(m0);
    *(short4v*)&mean_sp_bf[64 + s0g][i0g]  = pack4(m1);
    if (t < 64) *(short4v*)&mean_sp_bf[128 + s0g][i0g] = pack4(m2);

    const f32x4* s4 = (const f32x4*)srcc;
    f32x4 x0 = s4[t], x1 = s4[t + 256];
    short4v p0 = pack4(x0), p1 = pack4(x1);
    *(short4v*)&xs_bf[s0g + 2][i0g]      = p0;
    *(short4v*)&xs_bf[64 + s0g + 2][i0g] = p1;
    #pragma unroll
    for (int j = 0; j < 4; j++) {
        xT_bf[i0g + j][s0g]      = (unsigned short)p0[j];
        xT_bf[i0g + j][64 + s0g] = (unsigned short)p1[j];
    }
    if (t < 64) {
        f32x4 x2 = s4[t + 512];
        short4v p2 = pack4(x2);
        *(short4v*)&xs_bf[128 + s0g + 2][i0g] = p2;
        #pragma unroll
        for (int j = 0; j < 4; j++) xT_bf[i0g + j][128 + s0g] = (unsigned short)p2[j];
    }
    if (t < 64) {                                      // conv halo zeros
        int r = t >> 4, i = t & 15;
        int row = (r < 2) ? r : 144 + r;               // 0,1,146,147
        xs_bf[row][i] = 0;
    }
    if (t < 16) { sbl[t] = bl[t]; sfcb[t] = fcb[t]; }
    if (t < SEQn) sfbl[t] = fbl[t];
    __syncthreads();

    // ---- Stage 2: mean-MFMA + conv + spatial, balanced (14/13/13/14 MFMA) ----
    const int mst[4] = {0, 0, 3, 6}, mcn[4] = {0, 3, 3, 3};   // feature-mean s-tiles
    const int cst[4] = {0, 3, 5, 7}, ccn[4] = {3, 2, 2, 2};   // conv s-tiles
    const int sst[4] = {0, 2, 4, 6}, scn[4] = {2, 2, 2, 3};   // spatial s-tiles

    // feature mean: x(144x16,pad K32) @ adjacency(16x16) -> meanft[i][s]
    for (int tt = 0; tt < mcn[wave]; tt++) {
        int mt = mst[wave] + tt;
        int sl = mt * 16 + ln;
        bf16x8 a = {0,0,0,0,0,0,0,0};
        if (q < 2) a = *(const bf16x8*)&xs_bf[sl + 2][q * 8];
        f32x4 acc = {0.f,0.f,0.f,0.f};
        acc = MFMA(a, ftf, acc);
        *(short4v*)&meanft_bf[ln][mt * 16 + q * 4] = pack4(acc);  // col=i=ln, rows=s
    }
    // conv: K=128 im2col; B-frag = one b128 from haloed xs
    for (int tt = 0; tt < ccn[wave]; tt++) {
        int n0 = cst[wave] + tt;
        int sl = n0 * 16 + ln;
        f32x4 acc = {0.f,0.f,0.f,0.f};
        #pragma unroll
        for (int kk = 0; kk < 4; kk++) {
            int kkp = kk * 2 + (q >> 1);
            int off = (kkp < 3) ? (kkp - 1) : (kkp - 5);
            int i0 = (q & 1) * 8;
            bf16x8 bfr = *(const bf16x8*)&xs_bf[sl + 2 + off][i0];
            acc = MFMA(caf[kk], bfr, acc);
        }
        *(short4v*)&tp_bf[sl][q * 4] = pack4(acc);
    }
    // spatial: [mean_sp|x](144x32) @ [Wl;Wr](32x16)
    for (int tt = 0; tt < scn[wave]; tt++) {
        int mt = sst[wave] + tt;
        int sl = mt * 16 + ln;
        const unsigned short* ap = (q < 2) ? &mean_sp_bf[sl][(q & 1) * 8]
                                           : &xs_bf[sl + 2][(q & 1) * 8];
        bf16x8 a = *(const bf16x8*)ap;
        f32x4 acc = {0.f,0.f,0.f,0.f};
        acc = MFMA(a, sbf, acc);
        #pragma unroll
        for (int r = 0; r < 4; r++)
            sp_bf[mt * 16 + q * 4 + r][ln] = f2bf(acc[r] + sbl[ln]);
    }
    __syncthreads();

    // ---- Stage 3: feature GEMM (16x144 @ 144x144, K=288) ----
    const int fst[4] = {0, 3, 5, 7}, fcn[4] = {3, 2, 2, 2};
    for (int tt = 0; tt < fcn[wave]; tt++) {
        int n0 = fst[wave] + tt;
        int sl = n0 * 16 + ln;
        f32x4 acc = {0.f,0.f,0.f,0.f};
        #pragma unroll
        for (int kk = 0; kk < 9; kk++) {
            int koff = kk * 32 + q * 8;
            const unsigned short* ap = (koff < 144) ? &meanft_bf[ln][koff]
                                                    : &xT_bf[ln][koff - 144];
            bf16x8 a = *(const bf16x8*)ap;
            bf16x8 bfr = *(const bf16x8*)(featB + ((kk * 9 + n0) * 64 + lane) * 8);
            acc = MFMA(a, bfr, acc);
        }
        *(short4v*)&ff_bf[sl][q * 4] = pack4(acc + sfbl[sl]);
    }
    __syncthreads();

    // ---- Stage 4: FC (K=64: [sp|ff|tp|0]) + residual + store ----
    const int xst[4] = {0, 2, 4, 6}, xcn[4] = {2, 2, 2, 3};
    float* outb = out + (size_t)bc * (SEQn * INVn);
    for (int tt = 0; tt < xcn[wave]; tt++) {
        int mt = xst[wave] + tt;
        int sl = mt * 16 + ln;
        f32x4 acc = {0.f,0.f,0.f,0.f};
        {
            const unsigned short* ap = (q < 2) ? &sp_bf[sl][(q & 1) * 8]
                                               : &ff_bf[sl][(q & 1) * 8];
            bf16x8 a = *(const bf16x8*)ap;
            acc = MFMA(a, fcf0, acc);
        }
        {
            bf16x8 a = {0,0,0,0,0,0,0,0};
            if (q < 2) a = *(const bf16x8*)&tp_bf[sl][q * 8];
            acc = MFMA(a, fcf1, acc);
        }
        #pragma unroll
        for (int r = 0; r < 4; r++) {
            int so = mt * 16 + q * 4 + r;
            int idx = so * 16 + ln;
            outb[idx] = acc[r] + sfcb[ln] + srcc[idx];   // fp32 residual
        }
    }
}

extern "C" void kernel_launch(void* const* d_in, const int* in_sizes, int n_in,
                              void* d_out, int out_size, void* d_ws, size_t ws_size,
                              hipStream_t stream)
{
    const float* src = (const float*)d_in[0];
    const int* ge = (const int*)d_in[1];
    const int* fe = (const int*)d_in[2];
    const float* Wl  = (const float*)d_in[3];
    const float* blp = (const float*)d_in[4];
    const float* Wr  = (const float*)d_in[5];
    const float* fWl = (const float*)d_in[6];
    const float* fbl = (const float*)d_in[7];
    const float* fWr = (const float*)d_in[8];
    const float* w1  = (const float*)d_in[9];
    const float* w2  = (const float*)d_in[10];
    const float* fcw = (const float*)d_in[11];
    const float* fcb = (const float*)d_in[12];
    float* out = (float*)d_out;
    int* ws = (int*)d_ws;

    hipLaunchKernelGGL(prep_kernel, dim3(16), dim3(256), 0, stream,
                       ge, fe, Wl, Wr, fWl, fWr, w1, w2, fcw, ws);
    hipLaunchKernelGGL(fused_kernel, dim3(BZn * CAPn), dim3(256), 0, stream,
                       src, blp, fbl, fcb, ws, out);
}

// Round 5
// 171.606 us; speedup vs baseline: 5.8976x; 1.0219x over previous
//
#include <hip/hip_runtime.h>
#include <hip/hip_bf16.h>

#define BZn 32
#define CAPn 134
#define SEQn 144
#define INVn 16
#define ESP 1072
#define EFT 64

// ws layout (bytes):
// 0     : g_rp   135 ints
// 540   : g_col  1072 ints
// 4828  : g_inv  134 floats
// 5376  : uB     512 bf16 (1024 B)  — H1 = AdjW@F1 fragments, K=32 pad
// 6400  : vB     512 bf16           — F1 fragments, K=32 pad
// 7424  : spB2   512 bf16           — [Wl@F0 ; Wr@F0] fragments (K=32)
// 8448  : biasf  32 floats          — bias_i[16] (bl@F0+fcb), cs[16] (colsum F1)
// 8704  : convA2 2048 bf16 (4096 B) — conv weights ⊗ F2, A-fragments
// 12800 : featB  41472 bf16 (82944) — [fWl;fWr] B-fragments (K=288)
// end 95744

typedef __attribute__((ext_vector_type(8))) short bf16x8;
typedef __attribute__((ext_vector_type(4))) short short4v;
typedef __attribute__((ext_vector_type(4))) float f32x4;

#define MFMA(a, b, c) __builtin_amdgcn_mfma_f32_16x16x32_bf16(a, b, c, 0, 0, 0)

__device__ __forceinline__ unsigned short f2bf(float f) {
    union { float f; unsigned u; } v; v.f = f;
    unsigned r = v.u + 0x7fff + ((v.u >> 16) & 1);
    return (unsigned short)(r >> 16);
}
__device__ __forceinline__ float bf2f(unsigned short h) {
    union { unsigned u; float f; } v; v.u = ((unsigned)h) << 16;
    return v.f;
}
__device__ __forceinline__ unsigned pk2(float a, float b) {
    float2 v; v.x = a; v.y = b;
    union { __hip_bfloat162 h; unsigned u; } c;
    c.h = __float22bfloat162_rn(v);
    return c.u;
}
__device__ __forceinline__ short4v pack4(f32x4 v) {
    union { unsigned u[2]; short4v s; } r;
    r.u[0] = pk2(v[0], v[1]);
    r.u[1] = pk2(v[2], v[3]);
    return r.s;
}

// grid = 9. Block 0: CSR + all small weight combos. Block kk (0..8): featB slab
// kk via LDS staging (coalesced global reads AND writes — the old prep's 50 µs
// was 41k stride-576B scattered reads).
__global__ __launch_bounds__(256) void prep_kernel(
    const int* __restrict__ ge, const int* __restrict__ fe,
    const float* __restrict__ Wl,  const float* __restrict__ Wr,
    const float* __restrict__ fWl, const float* __restrict__ fWr,
    const float* __restrict__ w1,  const float* __restrict__ w2,
    const float* __restrict__ fcw, const float* __restrict__ bl,
    const float* __restrict__ fcb,
    int* __restrict__ ws)
{
    int t = threadIdx.x;
    char* wsb = (char*)ws;
    unsigned short* uB     = (unsigned short*)(wsb + 5376);
    unsigned short* vB     = (unsigned short*)(wsb + 6400);
    unsigned short* spB2   = (unsigned short*)(wsb + 7424);
    float*          biasf  = (float*)(wsb + 8448);
    unsigned short* convA2 = (unsigned short*)(wsb + 8704);
    unsigned short* featB  = (unsigned short*)(wsb + 12800);

    __shared__ float wtile[32][145];

    if (blockIdx.x == 0) {
        int* g_rp  = ws;
        int* g_col = ws + 135;
        float* g_inv = (float*)(ws + 1207);
        __shared__ int cnt[CAPn], off[CAPn], fm[256];
        __shared__ float finv[16];
        for (int c0 = t; c0 < CAPn; c0 += 256) cnt[c0] = 0;
        fm[t] = 0;
        __syncthreads();
        for (int e = t; e < ESP; e += 256) atomicAdd(&cnt[ge[ESP + e]], 1);
        if (t < EFT) atomicAdd(&fm[fe[t] * 16 + fe[EFT + t]], 1);
        __syncthreads();
        if (t == 0) {
            int run = 0;
            for (int c0 = 0; c0 < CAPn; c0++) {
                off[c0] = run; g_rp[c0] = run;
                g_inv[c0] = 1.0f / fmaxf((float)cnt[c0], 1.0f);
                run += cnt[c0];
            }
            g_rp[CAPn] = run;
        }
        if (t < 16) {
            int dg = 0;
            for (int j = 0; j < 16; j++) dg += fm[j * 16 + t];
            finv[t] = 1.0f / fmaxf((float)dg, 1.0f);
        }
        __syncthreads();
        for (int c0 = t; c0 < CAPn; c0 += 256) cnt[c0] = 0;
        __syncthreads();
        for (int e = t; e < ESP; e += 256) {
            int d = ge[ESP + e];
            int p = off[d] + atomicAdd(&cnt[d], 1);
            g_col[p] = ge[e];
        }
        // small combined-weight fragments (fm/finv already visible)
        for (int u = t; u < 512; u += 256) {
            int l = u >> 3, j = u & 7, k = (l >> 4) * 8 + j, ip = l & 15;
            float vu = 0.f, vv = 0.f, vs = 0.f;
            if (k < 16) {
                for (int i = 0; i < 16; i++)
                    vu += (float)fm[k * 16 + i] * finv[i] * fcw[(16 + i) * 16 + ip];
                vv = fcw[(16 + k) * 16 + ip];
                for (int i = 0; i < 16; i++) vs += Wl[k * 16 + i] * fcw[i * 16 + ip];
            } else {
                for (int i = 0; i < 16; i++) vs += Wr[(k - 16) * 16 + i] * fcw[i * 16 + ip];
            }
            uB[u] = f2bf(vu); vB[u] = f2bf(vv); spB2[u] = f2bf(vs);
        }
        for (int u = t; u < 2048; u += 256) {
            int kk2 = u >> 9, l = (u >> 3) & 63, j = u & 7, q = l >> 4, o = l & 15;
            int kkp = kk2 * 2 + (q >> 1), i = (q & 1) * 8 + j;
            float v = 0.f;
            for (int o0 = 0; o0 < 16; o0++) {
                float w = (kkp < 3) ? w1[(o0 * 16 + i) * 3 + kkp]
                                    : w2[(o0 * 16 + i) * 5 + (kkp - 3)];
                v += w * fcw[(32 + o0) * 16 + o];
            }
            convA2[u] = f2bf(v);
        }
        if (t < 16) {
            float b0 = fcb[t], c0 = 0.f;
            for (int i = 0; i < 16; i++) {
                b0 += bl[i] * fcw[i * 16 + t];
                c0 += fcw[(16 + i) * 16 + t];
            }
            biasf[t] = b0; biasf[16 + t] = c0;
        }
    }

    // featB slab kk: coalesced read -> LDS -> coalesced packed write
    int kk = blockIdx.x;
    for (int u = t; u < 32 * 144; u += 256) {
        int r = u / 144, s = u - r * 144;
        int k = kk * 32 + r;
        wtile[r][s] = (k < 144) ? fWl[k * 144 + s] : fWr[(k - 144) * 144 + s];
    }
    __syncthreads();
    for (int u = t; u < 4608; u += 256) {
        int n0 = u >> 9, rem = u & 511;
        int l = rem >> 3, j = rem & 7;
        featB[(kk * 9 + n0) * 512 + rem] = f2bf(wtile[(l >> 4) * 8 + j][n0 * 16 + (l & 15)]);
    }
}

__global__ __launch_bounds__(256, 5) void fused_kernel(
    const float* __restrict__ src,
    const float* __restrict__ fbl,
    const int* __restrict__ ws,
    float* __restrict__ out)
{
    const int* g_rp  = ws;
    const int* g_col = ws + 135;
    const float* g_inv = (const float*)(ws + 1207);
    const char* wsb = (const char*)ws;
    const unsigned short* uB     = (const unsigned short*)(wsb + 5376);
    const unsigned short* vB     = (const unsigned short*)(wsb + 6400);
    const unsigned short* spB2   = (const unsigned short*)(wsb + 7424);
    const float*          biasf  = (const float*)(wsb + 8448);
    const unsigned short* convA2 = (const unsigned short*)(wsb + 8704);
    const unsigned short* featB  = (const unsigned short*)(wsb + 12800);

    // ~31.6 KB LDS -> 5 blocks/CU. Strides 24/312 shorts: <=2-way banks (free).
    __shared__ __align__(16) unsigned short xs_bf[SEQn + 4][24];   // x[s][i] + conv halo
    __shared__ __align__(16) unsigned short msp_bf[SEQn][24];      // spatial mean [s][i]
    __shared__ __align__(16) unsigned short uv_bf[INVn][312];      // [U|V][i'][k=0..288)
    __shared__ __align__(16) unsigned short t_bf[SEQn][24];        // conv+feat sum [s][i']
    __shared__ float sfbl[SEQn], sbias[16], scs[16];

    int t = threadIdx.x;
    int wave = t >> 6, lane = t & 63;
    int q = lane >> 4, ln = lane & 15;

    // batch-major per XCD: concurrent blocks on an XCD share one 1.2 MB batch
    // slice -> gather re-reads are L2 hits
    int xcd  = blockIdx.x & 7;
    int slot = blockIdx.x >> 3;        // 0..535
    int bl_  = slot / 134;             // 0..3
    int c    = slot - bl_ * 134;
    int b    = xcd * 4 + bl_;
    int bc   = b * CAPn + c;
    const float* srcb = src + (size_t)b * (CAPn * SEQn * INVn);
    const float* srcc = srcb + (size_t)c * (SEQn * INVn);

    // hoisted tile-invariant fragments (L2-hot, no LDS dep)
    bf16x8 caf[4];
    #pragma unroll
    for (int kk = 0; kk < 4; kk++)
        caf[kk] = *(const bf16x8*)(convA2 + (kk * 64 + lane) * 8);
    bf16x8 sbf = *(const bf16x8*)(spB2 + lane * 8);
    bf16x8 ubf = *(const bf16x8*)(uB + lane * 8);
    bf16x8 vbf = *(const bf16x8*)(vB + lane * 8);

    // ---- Stage 1: float4 gather + staging ----
    int rs = g_rp[c], re = g_rp[c + 1];
    float idg = g_inv[c];
    f32x4 m0 = {0.f,0.f,0.f,0.f}, m1 = {0.f,0.f,0.f,0.f}, m2 = {0.f,0.f,0.f,0.f};
    for (int e = rs; e < re; e++) {
        int n = g_col[e];                              // block-uniform
        const f32x4* p4 = (const f32x4*)(srcb + (size_t)n * (SEQn * INVn));
        m0 += p4[t];
        m1 += p4[t + 256];
        if (t < 64) m2 += p4[t + 512];
    }
    int s0g = t >> 2, i0g = (t & 3) * 4;
    m0 *= idg; m1 *= idg; m2 *= idg;
    *(short4v*)&msp_bf[s0g][i0g]      = pack4(m0);
    *(short4v*)&msp_bf[64 + s0g][i0g] = pack4(m1);
    if (t < 64) *(short4v*)&msp_bf[128 + s0g][i0g] = pack4(m2);

    const f32x4* s4 = (const f32x4*)srcc;
    f32x4 x0 = s4[t], x1 = s4[t + 256];
    *(short4v*)&xs_bf[s0g + 2][i0g]      = pack4(x0);
    *(short4v*)&xs_bf[64 + s0g + 2][i0g] = pack4(x1);
    if (t < 64) {
        f32x4 x2 = s4[t + 512];
        *(short4v*)&xs_bf[128 + s0g + 2][i0g] = pack4(x2);
    }
    if (t < 64) {                                      // conv halo zeros
        int r = t >> 4, i = t & 15;
        int row = (r < 2) ? r : 144 + r;               // 0,1,146,147
        xs_bf[row][i] = 0;
    }
    if (t < SEQn) sfbl[t] = fbl[t];
    if (t < 16) { sbias[t] = biasf[t]; scs[t] = biasf[16 + t]; }
    __syncthreads();

    // ---- Stage A: U=x@H1, V=x@F1 (K=32 pad) + spatial GEMM (held in regs) ----
    const int ust[4] = {0, 3, 5, 7}, ucn[4] = {3, 2, 2, 2};
    for (int tt = 0; tt < ucn[wave]; tt++) {
        int mt = ust[wave] + tt;
        int sl = mt * 16 + ln;
        bf16x8 a = {0,0,0,0,0,0,0,0};
        if (q < 2) a = *(const bf16x8*)&xs_bf[sl + 2][q * 8];
        f32x4 au = {0.f,0.f,0.f,0.f}, av = {0.f,0.f,0.f,0.f};
        au = MFMA(a, ubf, au);
        av = MFMA(a, vbf, av);
        *(short4v*)&uv_bf[ln][mt * 16 + q * 4]       = pack4(au);
        *(short4v*)&uv_bf[ln][144 + mt * 16 + q * 4] = pack4(av);
    }
    const int sst[4] = {0, 2, 4, 6}, scn[4] = {2, 2, 2, 3};
    f32x4 accS[3];
    for (int tt = 0; tt < scn[wave]; tt++) {
        int mt = sst[wave] + tt;
        int sl = mt * 16 + ln;
        const unsigned short* ap = (q < 2) ? &msp_bf[sl][(q & 1) * 8]
                                           : &xs_bf[sl + 2][(q & 1) * 8];
        bf16x8 a = *(const bf16x8*)ap;
        f32x4 z = {0.f,0.f,0.f,0.f};
        accS[tt] = MFMA(a, sbf, z);
    }
    __syncthreads();

    // ---- Stage B: conv (4 MFMA) + feature K=288 (9 MFMA) per s-tile ----
    const int bst[4] = {0, 3, 5, 7}, bcn[4] = {3, 2, 2, 2};
    for (int tt = 0; tt < bcn[wave]; tt++) {
        int n0 = bst[wave] + tt;
        int sl = n0 * 16 + ln;
        f32x4 acc = {0.f,0.f,0.f,0.f};
        #pragma unroll
        for (int kk = 0; kk < 4; kk++) {
            int kkp = kk * 2 + (q >> 1);
            int off = (kkp < 3) ? (kkp - 1) : (kkp - 5);
            bf16x8 bb = *(const bf16x8*)&xs_bf[sl + 2 + off][(q & 1) * 8];
            acc = MFMA(caf[kk], bb, acc);
        }
        #pragma unroll
        for (int kk = 0; kk < 9; kk++) {
            bf16x8 a  = *(const bf16x8*)&uv_bf[ln][kk * 32 + q * 8];
            bf16x8 bb = *(const bf16x8*)(featB + ((kk * 9 + n0) * 64 + lane) * 8);
            acc = MFMA(a, bb, acc);
        }
        *(short4v*)&t_bf[sl][q * 4] = pack4(acc);     // [s][i'] via C-layout scatter
    }
    __syncthreads();

    // ---- Epilogue: spatial regs + t_bf + residual + bias, store ----
    float* outb = out + (size_t)bc * (SEQn * INVn);
    for (int tt = 0; tt < scn[wave]; tt++) {
        int mt = sst[wave] + tt;
        #pragma unroll
        for (int r = 0; r < 4; r++) {
            int s = mt * 16 + q * 4 + r;
            int idx = s * 16 + ln;
            outb[idx] = accS[tt][r] + bf2f(t_bf[s][ln]) + srcc[idx]
                      + sbias[ln] + sfbl[s] * scs[ln];
        }
    }
}

extern "C" void kernel_launch(void* const* d_in, const int* in_sizes, int n_in,
                              void* d_out, int out_size, void* d_ws, size_t ws_size,
                              hipStream_t stream)
{
    const float* src = (const float*)d_in[0];
    const int* ge = (const int*)d_in[1];
    const int* fe = (const int*)d_in[2];
    const float* Wl  = (const float*)d_in[3];
    const float* blp = (const float*)d_in[4];
    const float* Wr  = (const float*)d_in[5];
    const float* fWl = (const float*)d_in[6];
    const float* fbl = (const float*)d_in[7];
    const float* fWr = (const float*)d_in[8];
    const float* w1  = (const float*)d_in[9];
    const float* w2  = (const float*)d_in[10];
    const float* fcw = (const float*)d_in[11];
    const float* fcb = (const float*)d_in[12];
    float* out = (float*)d_out;
    int* ws = (int*)d_ws;

    hipLaunchKernelGGL(prep_kernel, dim3(9), dim3(256), 0, stream,
                       ge, fe, Wl, Wr, fWl, fWr, w1, w2, fcw, blp, fcb, ws);
    hipLaunchKernelGGL(fused_kernel, dim3(BZn * CAPn), dim3(256), 0, stream,
                       src, fbl, ws, out);
}

// Round 6
// 164.869 us; speedup vs baseline: 6.1386x; 1.0409x over previous
//
#include <hip/hip_runtime.h>
#include <hip/hip_bf16.h>

#define BZn 32
#define CAPn 134
#define SEQn 144
#define INVn 16
#define ESP 1072
#define EFT 64

// ws layout (bytes):
// 0     : g_rp   135 ints
// 540   : g_col  1072 ints
// 4828  : g_inv  134 floats
// 5376  : uB     512 bf16 (1024 B)  — H1 = AdjW@F1 fragments, K=32 pad
// 6400  : vB     512 bf16           — F1 fragments, K=32 pad
// 7424  : spB2   512 bf16           — [Wl@F0 ; Wr@F0] fragments (K=32)
// 8448  : biasf  32 floats          — bias_i[16] (bl@F0+fcb), cs[16] (colsum F1)
// 8704  : convA2 2048 bf16 (4096 B) — conv weights ⊗ F2, A-fragments
// 12800 : featB  41472 bf16 (82944) — [fWl;fWr] B-fragments (K=288)
// end 95744

typedef __attribute__((ext_vector_type(8))) short bf16x8;
typedef __attribute__((ext_vector_type(4))) short short4v;
typedef __attribute__((ext_vector_type(4))) float f32x4;

#define MFMA(a, b, c) __builtin_amdgcn_mfma_f32_16x16x32_bf16(a, b, c, 0, 0, 0)

__device__ __forceinline__ unsigned short f2bf(float f) {
    union { float f; unsigned u; } v; v.f = f;
    unsigned r = v.u + 0x7fff + ((v.u >> 16) & 1);
    return (unsigned short)(r >> 16);
}
__device__ __forceinline__ float bf2f(unsigned short h) {
    union { unsigned u; float f; } v; v.u = ((unsigned)h) << 16;
    return v.f;
}
__device__ __forceinline__ unsigned pk2(float a, float b) {
    float2 v; v.x = a; v.y = b;
    union { __hip_bfloat162 h; unsigned u; } c;
    c.h = __float22bfloat162_rn(v);
    return c.u;
}
__device__ __forceinline__ short4v pack4(f32x4 v) {
    union { unsigned u[2]; short4v s; } r;
    r.u[0] = pk2(v[0], v[1]);
    r.u[1] = pk2(v[2], v[3]);
    return r.s;
}

// grid = 10. Block 0: CSR + combos, ALL small weights LDS-staged first
// (R5 post-mortem: scattered cold scalar global loads in the combo loops were
// the ~60 µs prep cost). Blocks 1..9: featB slab kk via LDS staging.
__global__ __launch_bounds__(256) void prep_kernel(
    const int* __restrict__ ge, const int* __restrict__ fe,
    const float* __restrict__ Wl,  const float* __restrict__ Wr,
    const float* __restrict__ fWl, const float* __restrict__ fWr,
    const float* __restrict__ w1,  const float* __restrict__ w2,
    const float* __restrict__ fcw, const float* __restrict__ bl,
    const float* __restrict__ fcb,
    int* __restrict__ ws)
{
    int t = threadIdx.x;
    char* wsb = (char*)ws;
    unsigned short* uB     = (unsigned short*)(wsb + 5376);
    unsigned short* vB     = (unsigned short*)(wsb + 6400);
    unsigned short* spB2   = (unsigned short*)(wsb + 7424);
    float*          biasf  = (float*)(wsb + 8448);
    unsigned short* convA2 = (unsigned short*)(wsb + 8704);
    unsigned short* featB  = (unsigned short*)(wsb + 12800);

    if (blockIdx.x == 0) {
        int* g_rp  = ws;
        int* g_col = ws + 135;
        float* g_inv = (float*)(ws + 1207);
        // LDS-staged weights: fcw@0(768) w1@768(768) w2@1536(1280)
        // Wl@2816(256) Wr@3072(256) bl@3328(16) fcb@3344(16)
        __shared__ float swt[3360];
        __shared__ int cnt[CAPn], off[CAPn], fm[256];
        __shared__ float finv[16];

        for (int u = t; u < 768;  u += 256) swt[u]        = fcw[u];
        for (int u = t; u < 768;  u += 256) swt[768 + u]  = w1[u];
        for (int u = t; u < 1280; u += 256) swt[1536 + u] = w2[u];
        if (t < 256) swt[2816 + t] = Wl[t];
        if (t < 256) swt[3072 + t] = Wr[t];
        if (t < 16) swt[3328 + t] = bl[t];
        if (t < 16) swt[3344 + t] = fcb[t];

        for (int c0 = t; c0 < CAPn; c0 += 256) cnt[c0] = 0;
        fm[t] = 0;
        __syncthreads();
        for (int e = t; e < ESP; e += 256) atomicAdd(&cnt[ge[ESP + e]], 1);
        if (t < EFT) atomicAdd(&fm[fe[t] * 16 + fe[EFT + t]], 1);
        __syncthreads();
        if (t == 0) {
            int run = 0;
            for (int c0 = 0; c0 < CAPn; c0++) {
                off[c0] = run; g_rp[c0] = run;
                g_inv[c0] = 1.0f / fmaxf((float)cnt[c0], 1.0f);
                run += cnt[c0];
            }
            g_rp[CAPn] = run;
        }
        if (t < 16) {
            int dg = 0;
            for (int j = 0; j < 16; j++) dg += fm[j * 16 + t];
            finv[t] = 1.0f / fmaxf((float)dg, 1.0f);
        }
        __syncthreads();
        for (int c0 = t; c0 < CAPn; c0 += 256) cnt[c0] = 0;
        __syncthreads();
        for (int e = t; e < ESP; e += 256) {
            int d = ge[ESP + e];
            int p = off[d] + atomicAdd(&cnt[d], 1);
            g_col[p] = ge[e];
        }
        // combos — all operands now in LDS
        for (int u = t; u < 512; u += 256) {
            int l = u >> 3, j = u & 7, k = (l >> 4) * 8 + j, ip = l & 15;
            float vu = 0.f, vv = 0.f, vs = 0.f;
            if (k < 16) {
                for (int i = 0; i < 16; i++)
                    vu += (float)fm[k * 16 + i] * finv[i] * swt[(16 + i) * 16 + ip];
                vv = swt[(16 + k) * 16 + ip];
                for (int i = 0; i < 16; i++) vs += swt[2816 + k * 16 + i] * swt[i * 16 + ip];
            } else {
                for (int i = 0; i < 16; i++) vs += swt[3072 + (k - 16) * 16 + i] * swt[i * 16 + ip];
            }
            uB[u] = f2bf(vu); vB[u] = f2bf(vv); spB2[u] = f2bf(vs);
        }
        for (int u = t; u < 2048; u += 256) {
            int kk2 = u >> 9, l = (u >> 3) & 63, j = u & 7, q = l >> 4, o = l & 15;
            int kkp = kk2 * 2 + (q >> 1), i = (q & 1) * 8 + j;
            float v = 0.f;
            for (int o0 = 0; o0 < 16; o0++) {
                float w = (kkp < 3) ? swt[768 + (o0 * 16 + i) * 3 + kkp]
                                    : swt[1536 + (o0 * 16 + i) * 5 + (kkp - 3)];
                v += w * swt[(32 + o0) * 16 + o];
            }
            convA2[u] = f2bf(v);
        }
        if (t < 16) {
            float b0 = swt[3344 + t], c0 = 0.f;
            for (int i = 0; i < 16; i++) {
                b0 += swt[3328 + i] * swt[i * 16 + t];
                c0 += swt[(16 + i) * 16 + t];
            }
            biasf[t] = b0; biasf[16 + t] = c0;
        }
    } else {
        // featB slab kk: coalesced read -> LDS -> coalesced packed write
        __shared__ float wtile[32][145];
        int kk = blockIdx.x - 1;
        for (int u = t; u < 32 * 144; u += 256) {
            int r = u / 144, s = u - r * 144;
            int k = kk * 32 + r;
            wtile[r][s] = (k < 144) ? fWl[k * 144 + s] : fWr[(k - 144) * 144 + s];
        }
        __syncthreads();
        for (int u = t; u < 4608; u += 256) {
            int n0 = u >> 9, rem = u & 511;
            int l = rem >> 3, j = rem & 7;
            featB[(kk * 9 + n0) * 512 + rem] =
                f2bf(wtile[(l >> 4) * 8 + j][n0 * 16 + (l & 15)]);
        }
    }
}

__global__ __launch_bounds__(256, 5) void fused_kernel(
    const float* __restrict__ src,
    const float* __restrict__ fbl,
    const int* __restrict__ ws,
    float* __restrict__ out)
{
    const int* g_rp  = ws;
    const int* g_col = ws + 135;
    const float* g_inv = (const float*)(ws + 1207);
    const char* wsb = (const char*)ws;
    const unsigned short* uB     = (const unsigned short*)(wsb + 5376);
    const unsigned short* vB     = (const unsigned short*)(wsb + 6400);
    const unsigned short* spB2   = (const unsigned short*)(wsb + 7424);
    const float*          biasf  = (const float*)(wsb + 8448);
    const unsigned short* convA2 = (const unsigned short*)(wsb + 8704);
    const unsigned short* featB  = (const unsigned short*)(wsb + 12800);

    // ~31.6 KB LDS -> 5 blocks/CU. Strides 24/312 shorts: <=2-way banks (free).
    __shared__ __align__(16) unsigned short xs_bf[SEQn + 4][24];   // x[s][i] + conv halo
    __shared__ __align__(16) unsigned short msp_bf[SEQn][24];      // spatial mean [s][i]
    __shared__ __align__(16) unsigned short uv_bf[INVn][312];      // [U|V][i'][k=0..288)
    __shared__ __align__(16) unsigned short t_bf[SEQn][24];        // conv+feat sum [s][i']
    __shared__ float sfbl[SEQn], sbias[16], scs[16];

    int t = threadIdx.x;
    int wave = t >> 6, lane = t & 63;
    int q = lane >> 4, ln = lane & 15;

    // batch-major per XCD: concurrent blocks on an XCD share one 1.2 MB batch
    // slice -> gather re-reads are L2 hits
    int xcd  = blockIdx.x & 7;
    int slot = blockIdx.x >> 3;        // 0..535
    int bl_  = slot / 134;             // 0..3
    int c    = slot - bl_ * 134;
    int b    = xcd * 4 + bl_;
    int bc   = b * CAPn + c;
    const float* srcb = src + (size_t)b * (CAPn * SEQn * INVn);
    const float* srcc = srcb + (size_t)c * (SEQn * INVn);

    // issue own-slice staging loads first (independent of gather)
    const f32x4* s4 = (const f32x4*)srcc;
    f32x4 x0 = s4[t], x1 = s4[t + 256];
    f32x4 x2 = {0.f,0.f,0.f,0.f};
    if (t < 64) x2 = s4[t + 512];

    // hoisted tile-invariant fragments (L2-hot, no LDS dep)
    bf16x8 caf[4];
    #pragma unroll
    for (int kk = 0; kk < 4; kk++)
        caf[kk] = *(const bf16x8*)(convA2 + (kk * 64 + lane) * 8);
    bf16x8 sbf = *(const bf16x8*)(spB2 + lane * 8);
    bf16x8 ubf = *(const bf16x8*)(uB + lane * 8);
    bf16x8 vbf = *(const bf16x8*)(vB + lane * 8);

    // ---- Stage 1: float4 gather (2-way unrolled: two independent chains) ----
    int rs = g_rp[c], re = g_rp[c + 1];
    float idg = g_inv[c];
    f32x4 m0a = {0.f,0.f,0.f,0.f}, m1a = {0.f,0.f,0.f,0.f}, m2a = {0.f,0.f,0.f,0.f};
    f32x4 m0b = {0.f,0.f,0.f,0.f}, m1b = {0.f,0.f,0.f,0.f}, m2b = {0.f,0.f,0.f,0.f};
    int e = rs;
    for (; e + 1 < re; e += 2) {
        int na = g_col[e], nb = g_col[e + 1];
        const f32x4* pa = (const f32x4*)(srcb + (size_t)na * (SEQn * INVn));
        const f32x4* pb = (const f32x4*)(srcb + (size_t)nb * (SEQn * INVn));
        m0a += pa[t];       m0b += pb[t];
        m1a += pa[t + 256]; m1b += pb[t + 256];
        if (t < 64) { m2a += pa[t + 512]; m2b += pb[t + 512]; }
    }
    if (e < re) {
        int na = g_col[e];
        const f32x4* pa = (const f32x4*)(srcb + (size_t)na * (SEQn * INVn));
        m0a += pa[t]; m1a += pa[t + 256];
        if (t < 64) m2a += pa[t + 512];
    }
    int s0g = t >> 2, i0g = (t & 3) * 4;
    f32x4 m0 = (m0a + m0b) * idg, m1 = (m1a + m1b) * idg, m2 = (m2a + m2b) * idg;
    *(short4v*)&msp_bf[s0g][i0g]      = pack4(m0);
    *(short4v*)&msp_bf[64 + s0g][i0g] = pack4(m1);
    if (t < 64) *(short4v*)&msp_bf[128 + s0g][i0g] = pack4(m2);

    *(short4v*)&xs_bf[s0g + 2][i0g]      = pack4(x0);
    *(short4v*)&xs_bf[64 + s0g + 2][i0g] = pack4(x1);
    if (t < 64) *(short4v*)&xs_bf[128 + s0g + 2][i0g] = pack4(x2);
    if (t < 64) {                                      // conv halo zeros
        int r = t >> 4, i = t & 15;
        int row = (r < 2) ? r : 144 + r;               // 0,1,146,147
        xs_bf[row][i] = 0;
    }
    if (t < SEQn) sfbl[t] = fbl[t];
    if (t < 16) { sbias[t] = biasf[t]; scs[t] = biasf[16 + t]; }
    __syncthreads();

    // ---- Stage A: U=x@H1, V=x@F1 (K=32 pad) + spatial GEMM (held in regs) ----
    const int ust[4] = {0, 3, 5, 7}, ucn[4] = {3, 2, 2, 2};
    for (int tt = 0; tt < ucn[wave]; tt++) {
        int mt = ust[wave] + tt;
        int sl = mt * 16 + ln;
        bf16x8 a = {0,0,0,0,0,0,0,0};
        if (q < 2) a = *(const bf16x8*)&xs_bf[sl + 2][q * 8];
        f32x4 au = {0.f,0.f,0.f,0.f}, av = {0.f,0.f,0.f,0.f};
        au = MFMA(a, ubf, au);
        av = MFMA(a, vbf, av);
        *(short4v*)&uv_bf[ln][mt * 16 + q * 4]       = pack4(au);
        *(short4v*)&uv_bf[ln][144 + mt * 16 + q * 4] = pack4(av);
    }
    const int sst[4] = {0, 2, 4, 6}, scn[4] = {2, 2, 2, 3};
    f32x4 accS[3];
    for (int tt = 0; tt < scn[wave]; tt++) {
        int mt = sst[wave] + tt;
        int sl = mt * 16 + ln;
        const unsigned short* ap = (q < 2) ? &msp_bf[sl][(q & 1) * 8]
                                           : &xs_bf[sl + 2][(q & 1) * 8];
        bf16x8 a = *(const bf16x8*)ap;
        f32x4 z = {0.f,0.f,0.f,0.f};
        accS[tt] = MFMA(a, sbf, z);
    }
    __syncthreads();

    // ---- Stage B: conv (4 MFMA) + feature K=288 (9 MFMA) per s-tile ----
    const int bst[4] = {0, 3, 5, 7}, bcn[4] = {3, 2, 2, 2};
    for (int tt = 0; tt < bcn[wave]; tt++) {
        int n0 = bst[wave] + tt;
        int sl = n0 * 16 + ln;
        f32x4 acc = {0.f,0.f,0.f,0.f};
        #pragma unroll
        for (int kk = 0; kk < 4; kk++) {
            int kkp = kk * 2 + (q >> 1);
            int off = (kkp < 3) ? (kkp - 1) : (kkp - 5);
            bf16x8 bb = *(const bf16x8*)&xs_bf[sl + 2 + off][(q & 1) * 8];
            acc = MFMA(caf[kk], bb, acc);
        }
        #pragma unroll
        for (int kk = 0; kk < 9; kk++) {
            bf16x8 a  = *(const bf16x8*)&uv_bf[ln][kk * 32 + q * 8];
            bf16x8 bb = *(const bf16x8*)(featB + ((kk * 9 + n0) * 64 + lane) * 8);
            acc = MFMA(a, bb, acc);
        }
        *(short4v*)&t_bf[sl][q * 4] = pack4(acc);     // [s][i'] via C-layout scatter
    }
    __syncthreads();

    // ---- Epilogue: spatial regs + t_bf + residual + bias, store ----
    float* outb = out + (size_t)bc * (SEQn * INVn);
    for (int tt = 0; tt < scn[wave]; tt++) {
        int mt = sst[wave] + tt;
        #pragma unroll
        for (int r = 0; r < 4; r++) {
            int s = mt * 16 + q * 4 + r;
            int idx = s * 16 + ln;
            outb[idx] = accS[tt][r] + bf2f(t_bf[s][ln]) + srcc[idx]
                      + sbias[ln] + sfbl[s] * scs[ln];
        }
    }
}

extern "C" void kernel_launch(void* const* d_in, const int* in_sizes, int n_in,
                              void* d_out, int out_size, void* d_ws, size_t ws_size,
                              hipStream_t stream)
{
    const float* src = (const float*)d_in[0];
    const int* ge = (const int*)d_in[1];
    const int* fe = (const int*)d_in[2];
    const float* Wl  = (const float*)d_in[3];
    const float* blp = (const float*)d_in[4];
    const float* Wr  = (const float*)d_in[5];
    const float* fWl = (const float*)d_in[6];
    const float* fbl = (const float*)d_in[7];
    const float* fWr = (const float*)d_in[8];
    const float* w1  = (const float*)d_in[9];
    const float* w2  = (const float*)d_in[10];
    const float* fcw = (const float*)d_in[11];
    const float* fcb = (const float*)d_in[12];
    float* out = (float*)d_out;
    int* ws = (int*)d_ws;

    hipLaunchKernelGGL(prep_kernel, dim3(10), dim3(256), 0, stream,
                       ge, fe, Wl, Wr, fWl, fWr, w1, w2, fcw, blp, fcb, ws);
    hipLaunchKernelGGL(fused_kernel, dim3(BZn * CAPn), dim3(256), 0, stream,
                       src, fbl, ws, out);
}